// Round 5
// baseline (1048.132 us; speedup 1.0000x reference)
//
#include <hip/hip_runtime.h>

// NodeMPNNLayer — R5: dst-sorted edge processing, run-compressed atomics.
//   prep_pq:  W->bf16 swizzled (WT) + P'=x@W1a+b1, Q=x@W1c (C-frag-permuted).
//   hist/scan/scatter: counting sort of edges by dst -> permE/permSrc/permDst.
//   edge_mfma: 250 blocks x 512 thr x 10 tiles x 256 sorted edges. W resident
//     in 96 KB LDS, 8 KB/wave act buffer. Coalesced ea row staging via perm.
//     P/Q gathers hidden behind layer-1 MFMA (added at epi1). Epilogue:
//     lane-local same-dst run compression -> few L2-hot atomics. No cnt
//     atomics (cnt == hist).
//   node_fused: dh=sums/max(hist,1); LN; FF; LN (fp32).

#define NE 640000
#define NN 10000
#define DD 128
#define HIDN 256
#define EPSF 1e-6f
#define TILES5 10
#define EBLK5 250   // 250 * 10 * 256 == NE

typedef __attribute__((ext_vector_type(8))) short short8;
typedef __attribute__((ext_vector_type(4))) float f32x4;

__device__ __forceinline__ unsigned short f2bf(float f) {
    union { float f; unsigned int u; } v; v.f = f;
    unsigned int r = v.u + 0x7FFFu + ((v.u >> 16) & 1u);
    return (unsigned short)(r >> 16);
}
__device__ __forceinline__ float bf2f(unsigned short h) {
    union { unsigned int u; float f; } v; v.u = ((unsigned int)h) << 16;
    return v.f;
}
__device__ __forceinline__ int swzcol(int row, int col) {
    return (((col >> 3) ^ (row & 7)) << 3) | (col & 7);
}
__device__ __forceinline__ const short8* frag(const unsigned short* buf,
                                              int row, int kc, int q) {
    int g = (kc * 4 + q) ^ (row & 7);
    return (const short8*)(buf + row * 128 + g * 8);
}

// ---------------------------------------------------------------------------
// prep (192 blocks) + pq (625 blocks).  Pp/Qp stored C-fragment-permuted:
// value of column j lands at in-row position pj = ((j&15)<<3)|(j>>4).
// Threads own the STORE position s (coalesced stores); j = inverse(s).
// ---------------------------------------------------------------------------
__global__ __launch_bounds__(256)
void prep_pq(const float* __restrict__ W1, const float* __restrict__ W2,
             const float* __restrict__ W3, const float* __restrict__ b1,
             const float* __restrict__ x,
             unsigned short* __restrict__ WT,
             unsigned short* __restrict__ Pp, unsigned short* __restrict__ Qp)
{
    const int t = threadIdx.x;
    if (blockIdx.x < 192) {
        int g = blockIdx.x * 256 + t;            // 3*16384 = 49152
        int layer = g >> 14, r = g & 16383;
        int n = r >> 7, k = r & 127;
        const float* W = (layer == 0) ? (W1 + 128 * DD) : (layer == 1 ? W2 : W3);
        WT[layer * 16384 + n * 128 + swzcol(n, k)] = f2bf(W[k * DD + n]);
        return;
    }
    __shared__ float sx[16][DD];
    const int nb = (blockIdx.x - 192) * 16;

#pragma unroll
    for (int p = 0; p < 2; ++p) {
        int f = t + p * 256;                     // 512 float4 = 16 rows x 32
        int row = f >> 5, c4 = (f & 31) << 2;
        *(float4*)&sx[row][c4] = *(const float4*)(x + (long)(nb + row) * DD + c4);
    }
    __syncthreads();

    const int s  = t & 127;                      // store position
    const int j  = ((s & 7) << 4) | (s >> 3);    // original column
    const int g8 = (t >> 7) << 3;

    for (int pass = 0; pass < 2; ++pass) {
        const float* W = W1 + (pass ? 256 * DD : 0);
        float acc[8];
#pragma unroll
        for (int v = 0; v < 8; ++v) acc[v] = 0.f;
        for (int k4 = 0; k4 < DD; k4 += 4) {
            float w0 = W[(k4 + 0) * DD + j];
            float w1 = W[(k4 + 1) * DD + j];
            float w2 = W[(k4 + 2) * DD + j];
            float w3 = W[(k4 + 3) * DD + j];
#pragma unroll
            for (int v = 0; v < 8; ++v) {
                float4 hv = *(const float4*)&sx[g8 + v][k4];
                acc[v] = fmaf(hv.x, w0, acc[v]);
                acc[v] = fmaf(hv.y, w1, acc[v]);
                acc[v] = fmaf(hv.z, w2, acc[v]);
                acc[v] = fmaf(hv.w, w3, acc[v]);
            }
        }
        unsigned short* Out = pass ? Qp : Pp;
        float bb = pass ? 0.f : b1[j];
#pragma unroll
        for (int v = 0; v < 8; ++v)
            Out[(long)(nb + g8 + v) * 128 + s] = f2bf(acc[v] + bb);
    }
}

// ---------------------------------------------------------------------------
// Counting sort of edges by dst.
// ---------------------------------------------------------------------------
__global__ __launch_bounds__(256)
void hist_kernel(const int* __restrict__ ei, int* __restrict__ hist)
{
    int e = blockIdx.x * 256 + threadIdx.x;
    atomicAdd(hist + ei[(long)NE + e], 1);
}

__global__ __launch_bounds__(256)
void scan_kernel(const int* __restrict__ hist, int* __restrict__ ofs)
{
    __shared__ int wsum[4];
    __shared__ int carry;
    const int t = threadIdx.x, w = t >> 6, l = t & 63;
    if (t == 0) carry = 0;
    __syncthreads();
    for (int base = 0; base < NN; base += 256) {
        int v = (base + t < NN) ? hist[base + t] : 0;
        int inc = v;
#pragma unroll
        for (int off = 1; off < 64; off <<= 1) {
            int u = __shfl_up(inc, off);
            if (l >= off) inc += u;
        }
        if (l == 63) wsum[w] = inc;
        __syncthreads();
        int add = 0;
        for (int i = 0; i < 4; ++i) if (i < w) add += wsum[i];
        if (base + t < NN) ofs[base + t] = carry + add + inc - v;
        __syncthreads();
        if (t == 255) carry += wsum[0] + wsum[1] + wsum[2] + wsum[3];
        __syncthreads();
    }
}

__global__ __launch_bounds__(256)
void scatter_kernel(const int* __restrict__ ei, int* __restrict__ ofs,
                    int* __restrict__ permE, int* __restrict__ permSrc,
                    int* __restrict__ permDst)
{
    int e = blockIdx.x * 256 + threadIdx.x;
    int sN = ei[e];
    int d  = ei[(long)NE + e];
    int pos = atomicAdd(ofs + d, 1);
    permE[pos]   = e;
    permSrc[pos] = sN;
    permDst[pos] = d;
}

// ---------------------------------------------------------------------------
// Edge kernel: 512 threads (8 waves), wave w owns rows [32w,32w+32) of each
// 256-edge sorted tile. Barrier-free after W load.
// ---------------------------------------------------------------------------
__global__ __launch_bounds__(512, 2)
void edge_mfma(const float* __restrict__ ea,
               const int* __restrict__ permE, const int* __restrict__ permSrc,
               const int* __restrict__ permDst,
               const unsigned short* __restrict__ WT,
               const unsigned short* __restrict__ Pp,
               const unsigned short* __restrict__ Qp,
               const float* __restrict__ b2, const float* __restrict__ b3,
               float* __restrict__ sums)
{
    __shared__ unsigned short sW[3 * 16384];     // 96 KB
    __shared__ unsigned short sAct[8 * 4096];    // 64 KB (8 KB per wave)

    const int t = threadIdx.x;
    const int wave = t >> 6, lane = t & 63;
    const int ln = lane & 15, q = lane >> 4;
    const int hi = lane >> 5, lo = lane & 31;
    unsigned short* myA = sAct + wave * 4096;

    {   // one-time W load — the ONLY __syncthreads
        const uint4* s = (const uint4*)WT;
        uint4* d = (uint4*)sW;
#pragma unroll
        for (int p = 0; p < 12; ++p) d[t + p * 512] = s[t + p * 512];
    }
    __syncthreads();

    int rowoff[8];
#pragma unroll
    for (int r = 0; r < 8; ++r) rowoff[r] = (r >> 2) * 16 + q * 4 + (r & 3);

    float bv2[8], bv3[8];
#pragma unroll
    for (int ct = 0; ct < 8; ++ct) {
        bv2[ct] = b2[ct * 16 + ln];
        bv3[ct] = b3[ct * 16 + ln];
    }

    const long blkbase = (long)blockIdx.x * (TILES5 * 256);
    const int r0g = wave * 32;

    // ---- prefetch tile 0: perm rows, meta, ea rows ----
    int prow[16], dstR[8], srcR[8];
    float4 Aq[16];
    {
        long tb = blkbase + r0g;
#pragma unroll
        for (int jj = 0; jj < 16; ++jj) prow[jj] = permE[tb + 2 * jj + hi];
#pragma unroll
        for (int r = 0; r < 8; ++r) {
            dstR[r] = permDst[tb + rowoff[r]];
            srcR[r] = permSrc[tb + rowoff[r]];
        }
#pragma unroll
        for (int jj = 0; jj < 16; ++jj)
            Aq[jj] = *(const float4*)(ea + (long)prow[jj] * DD + lo * 4);
    }

    for (int it = 0; it < TILES5; ++it) {
        // ---- P/Q gathers for current tile (consumed at epi1) ----
        uint4 pv[8], qv[8];
#pragma unroll
        for (int r = 0; r < 8; ++r) {
            pv[r] = *(const uint4*)(Pp + (long)dstR[r] * 128 + ln * 8);
            qv[r] = *(const uint4*)(Qp + (long)srcR[r] * 128 + ln * 8);
        }

        // ---- stage current A tile (regs -> bf16 swizzled LDS) ----
#pragma unroll
        for (int jj = 0; jj < 16; ++jj) {
            int srow = 2 * jj + hi, c4 = lo * 4;
            float4 v = Aq[jj];
            uint2 pk;
            pk.x = (unsigned)f2bf(v.x) | ((unsigned)f2bf(v.y) << 16);
            pk.y = (unsigned)f2bf(v.z) | ((unsigned)f2bf(v.w) << 16);
            *(uint2*)(myA + srow * 128 + swzcol(srow, c4)) = pk;
        }
        __builtin_amdgcn_wave_barrier();

        // ---- next-tile meta (sequential, cheap) ----
        long nb = blkbase + (long)((it + 1 < TILES5) ? it + 1 : it) * 256 + r0g;
        int nprow[16], ndst[8], nsrc[8];
#pragma unroll
        for (int jj = 0; jj < 16; ++jj) nprow[jj] = permE[nb + 2 * jj + hi];
#pragma unroll
        for (int r = 0; r < 8; ++r) {
            ndst[r] = permDst[nb + rowoff[r]];
            nsrc[r] = permSrc[nb + rowoff[r]];
        }

        // ---- layer 1: acc = bf16(ea) @ W1b^T ----
        f32x4 acc[2][8];
#pragma unroll
        for (int rt = 0; rt < 2; ++rt)
#pragma unroll
            for (int ct = 0; ct < 8; ++ct) acc[rt][ct] = (f32x4)(0.f);
#pragma unroll
        for (int kc = 0; kc < 4; ++kc) {
            short8 a0 = *frag(myA, ln, kc, q);
            short8 a1 = *frag(myA, 16 + ln, kc, q);
#pragma unroll
            for (int ct = 0; ct < 8; ++ct) {
                short8 b = *frag(sW, ct * 16 + ln, kc, q);
                acc[0][ct] = __builtin_amdgcn_mfma_f32_16x16x32_bf16(a0, b, acc[0][ct], 0, 0, 0);
                acc[1][ct] = __builtin_amdgcn_mfma_f32_16x16x32_bf16(a1, b, acc[1][ct], 0, 0, 0);
            }
        }

        // ---- prefetch next-tile ea rows ----
#pragma unroll
        for (int jj = 0; jj < 16; ++jj)
            Aq[jj] = *(const float4*)(ea + (long)nprow[jj] * DD + lo * 4);

        __builtin_amdgcn_wave_barrier();
        // epi1: relu(acc + P'[dst] + Q[src]) -> act
#pragma unroll
        for (int r = 0; r < 8; ++r) {
            const unsigned short* pe = (const unsigned short*)&pv[r];
            const unsigned short* qe = (const unsigned short*)&qv[r];
            int row = rowoff[r];
#pragma unroll
            for (int ct = 0; ct < 8; ++ct) {
                float v = acc[r >> 2][ct][r & 3] + bf2f(pe[ct]) + bf2f(qe[ct]);
                myA[row * 128 + swzcol(row, ct * 16 + ln)] = f2bf(fmaxf(v, 0.f));
            }
        }
        __builtin_amdgcn_wave_barrier();

        // ---- layer 2 ----
#pragma unroll
        for (int rt = 0; rt < 2; ++rt)
#pragma unroll
            for (int ct = 0; ct < 8; ++ct) acc[rt][ct] = (f32x4)(0.f);
#pragma unroll
        for (int kc = 0; kc < 4; ++kc) {
            short8 a0 = *frag(myA, ln, kc, q);
            short8 a1 = *frag(myA, 16 + ln, kc, q);
#pragma unroll
            for (int ct = 0; ct < 8; ++ct) {
                short8 b = *frag(sW + 16384, ct * 16 + ln, kc, q);
                acc[0][ct] = __builtin_amdgcn_mfma_f32_16x16x32_bf16(a0, b, acc[0][ct], 0, 0, 0);
                acc[1][ct] = __builtin_amdgcn_mfma_f32_16x16x32_bf16(a1, b, acc[1][ct], 0, 0, 0);
            }
        }
        __builtin_amdgcn_wave_barrier();
        // epi2: relu(acc + b2) -> act
#pragma unroll
        for (int r = 0; r < 8; ++r) {
            int row = rowoff[r];
#pragma unroll
            for (int ct = 0; ct < 8; ++ct) {
                float v = fmaxf(acc[r >> 2][ct][r & 3] + bv2[ct], 0.f);
                myA[row * 128 + swzcol(row, ct * 16 + ln)] = f2bf(v);
            }
        }
        __builtin_amdgcn_wave_barrier();

        // ---- layer 3 ----
#pragma unroll
        for (int rt = 0; rt < 2; ++rt)
#pragma unroll
            for (int ct = 0; ct < 8; ++ct) acc[rt][ct] = (f32x4)(0.f);
#pragma unroll
        for (int kc = 0; kc < 4; ++kc) {
            short8 a0 = *frag(myA, ln, kc, q);
            short8 a1 = *frag(myA, 16 + ln, kc, q);
#pragma unroll
            for (int ct = 0; ct < 8; ++ct) {
                short8 b = *frag(sW + 32768, ct * 16 + ln, kc, q);
                acc[0][ct] = __builtin_amdgcn_mfma_f32_16x16x32_bf16(a0, b, acc[0][ct], 0, 0, 0);
                acc[1][ct] = __builtin_amdgcn_mfma_f32_16x16x32_bf16(a1, b, acc[1][ct], 0, 0, 0);
            }
        }

        // epi3: +b3, then lane-local run-compressed scatter-add.
        // The 4 rows rg=0..3 (fixed rt) are lane-local and dst-sorted.
#pragma unroll
        for (int rt = 0; rt < 2; ++rt)
#pragma unroll
            for (int ct = 0; ct < 8; ++ct)
#pragma unroll
                for (int rg = 0; rg < 4; ++rg)
                    acc[rt][ct][rg] += bv3[ct];
#pragma unroll
        for (int rt = 0; rt < 2; ++rt) {
            int d = dstR[rt * 4];
            float run[8];
#pragma unroll
            for (int ct = 0; ct < 8; ++ct) run[ct] = acc[rt][ct][0];
#pragma unroll
            for (int rg = 1; rg < 4; ++rg) {
                int dn = dstR[rt * 4 + rg];
                if (dn == d) {
#pragma unroll
                    for (int ct = 0; ct < 8; ++ct) run[ct] += acc[rt][ct][rg];
                } else {
                    long o = (long)d * DD;
#pragma unroll
                    for (int ct = 0; ct < 8; ++ct)
                        atomicAdd(sums + o + ct * 16 + ln, run[ct]);
                    d = dn;
#pragma unroll
                    for (int ct = 0; ct < 8; ++ct) run[ct] = acc[rt][ct][rg];
                }
            }
            long o = (long)d * DD;
#pragma unroll
            for (int ct = 0; ct < 8; ++ct)
                atomicAdd(sums + o + ct * 16 + ln, run[ct]);
        }

#pragma unroll
        for (int jj = 0; jj < 16; ++jj) prow[jj] = nprow[jj];
#pragma unroll
        for (int r = 0; r < 8; ++r) { dstR[r] = ndst[r]; srcR[r] = nsrc[r]; }
    }
}

// ---------------------------------------------------------------------------
// Node stage: dh + LN1 + FF + LN2, fp32, 8 nodes/block. cnt from hist.
// ---------------------------------------------------------------------------
__global__ __launch_bounds__(256)
void node_fused(const float* __restrict__ x,
                const float* __restrict__ sums, const int* __restrict__ hist,
                const float* __restrict__ F1, const float* __restrict__ bf1,
                const float* __restrict__ F2, const float* __restrict__ bf2,
                const float* __restrict__ g0, const float* __restrict__ be0,
                const float* __restrict__ g1, const float* __restrict__ be1,
                float* __restrict__ out)
{
    constexpr int NPB = 8;
    __shared__ float sh[NPB][DD];
    __shared__ float shid[NPB][HIDN];
    __shared__ float sz[NPB][DD];

    const int t = threadIdx.x;
    const int wave = t >> 6, lane = t & 63;
    const int half = lane >> 5, l2 = lane & 31;
    const int nl = wave * 2 + half;
    const int node = blockIdx.x * NPB + nl;
    const long base = (long)node * DD;

    float inv = 1.0f / fmaxf((float)hist[node], 1.0f);
    float y[4], s = 0.f, ss = 0.f;
#pragma unroll
    for (int e = 0; e < 4; ++e) {
        int c = l2 + 32 * e;
        y[e] = x[base + c] + sums[base + c] * inv;
        s += y[e]; ss += y[e] * y[e];
    }
#pragma unroll
    for (int off = 16; off > 0; off >>= 1) {
        s += __shfl_down(s, off, 32); ss += __shfl_down(ss, off, 32);
    }
    s = __shfl(s, 0, 32); ss = __shfl(ss, 0, 32);
    float mean = s * (1.0f / DD);
    float var  = ss * (1.0f / DD) - mean * mean;
    float rstd = rsqrtf(var + EPSF);
#pragma unroll
    for (int e = 0; e < 4; ++e) {
        int c = l2 + 32 * e;
        sh[nl][c] = (y[e] - mean) * rstd * g0[c] + be0[c];
    }
    __syncthreads();

    float hacc[NPB];
    float bb = bf1[t];
#pragma unroll
    for (int v = 0; v < NPB; ++v) hacc[v] = bb;
    for (int k4 = 0; k4 < DD; k4 += 4) {
        float w0 = F1[(long)(k4 + 0) * HIDN + t];
        float w1 = F1[(long)(k4 + 1) * HIDN + t];
        float w2 = F1[(long)(k4 + 2) * HIDN + t];
        float w3 = F1[(long)(k4 + 3) * HIDN + t];
#pragma unroll
        for (int v = 0; v < NPB; ++v) {
            float4 hv = *(const float4*)&sh[v][k4];
            hacc[v] = fmaf(hv.x, w0, hacc[v]);
            hacc[v] = fmaf(hv.y, w1, hacc[v]);
            hacc[v] = fmaf(hv.z, w2, hacc[v]);
            hacc[v] = fmaf(hv.w, w3, hacc[v]);
        }
    }
#pragma unroll
    for (int v = 0; v < NPB; ++v) shid[v][t] = fmaxf(hacc[v], 0.f);
    __syncthreads();

    const int col = t & (DD - 1);
    const int grp = (t >> 7) * 4;
    float o[4];
#pragma unroll
    for (int v = 0; v < 4; ++v) o[v] = bf2[col];
    for (int k4 = 0; k4 < HIDN; k4 += 4) {
        float w0 = F2[(long)(k4 + 0) * DD + col];
        float w1 = F2[(long)(k4 + 1) * DD + col];
        float w2 = F2[(long)(k4 + 2) * DD + col];
        float w3 = F2[(long)(k4 + 3) * DD + col];
#pragma unroll
        for (int v = 0; v < 4; ++v) {
            float4 hv = *(const float4*)&shid[grp + v][k4];
            o[v] = fmaf(hv.x, w0, o[v]);
            o[v] = fmaf(hv.y, w1, o[v]);
            o[v] = fmaf(hv.z, w2, o[v]);
            o[v] = fmaf(hv.w, w3, o[v]);
        }
    }
#pragma unroll
    for (int v = 0; v < 4; ++v) sz[grp + v][col] = sh[grp + v][col] + o[v];
    __syncthreads();

    float z[4]; s = 0.f; ss = 0.f;
#pragma unroll
    for (int e = 0; e < 4; ++e) {
        int c = l2 + 32 * e;
        z[e] = sz[nl][c]; s += z[e]; ss += z[e] * z[e];
    }
#pragma unroll
    for (int off = 16; off > 0; off >>= 1) {
        s += __shfl_down(s, off, 32); ss += __shfl_down(ss, off, 32);
    }
    s = __shfl(s, 0, 32); ss = __shfl(ss, 0, 32);
    mean = s * (1.0f / DD);
    var  = ss * (1.0f / DD) - mean * mean;
    rstd = rsqrtf(var + EPSF);
#pragma unroll
    for (int e = 0; e < 4; ++e) {
        int c = l2 + 32 * e;
        out[base + c] = (z[e] - mean) * rstd * g1[c] + be1[c];
    }
}

extern "C" void kernel_launch(void* const* d_in, const int* in_sizes, int n_in,
                              void* d_out, int out_size, void* d_ws, size_t ws_size,
                              hipStream_t stream)
{
    const float* x   = (const float*)d_in[0];
    const int*   ei  = (const int*)  d_in[1];
    const float* ea  = (const float*)d_in[2];
    const float* W1  = (const float*)d_in[3];
    const float* b1  = (const float*)d_in[4];
    const float* W2  = (const float*)d_in[5];
    const float* b2  = (const float*)d_in[6];
    const float* W3  = (const float*)d_in[7];
    const float* b3  = (const float*)d_in[8];
    const float* F1  = (const float*)d_in[9];
    const float* bf1 = (const float*)d_in[10];
    const float* F2  = (const float*)d_in[11];
    const float* bf2 = (const float*)d_in[12];
    const float* g0  = (const float*)d_in[13];
    const float* be0 = (const float*)d_in[14];
    const float* g1  = (const float*)d_in[15];
    const float* be1 = (const float*)d_in[16];
    float* out = (float*)d_out;

    char* ws = (char*)d_ws;
    float*          sums    = (float*)(ws);                      // 5,120,000
    int*            hist    = (int*)  (ws + 5120000);            //    40,000
    unsigned short* WT      = (unsigned short*)(ws + 5160192);   //    98,304
    unsigned short* Pp      = (unsigned short*)(ws + 5258752);   // 2,560,000
    unsigned short* Qp      = (unsigned short*)(ws + 7818752);   // 2,560,000
    int*            ofs     = (int*)  (ws + 10378752);           //    40,000
    int*            permE   = (int*)  (ws + 10418944);           // 2,560,000
    int*            permSrc = (int*)  (ws + 12978944);           // 2,560,000
    int*            permDst = (int*)  (ws + 15538944);           // 2,560,000
    // total ~18.1 MB

    hipMemsetAsync(ws, 0, 5160000, stream);                      // sums + hist
    prep_pq<<<192 + NN / 16, 256, 0, stream>>>(W1, W2, W3, b1, x, WT, Pp, Qp);
    hist_kernel<<<NE / 256, 256, 0, stream>>>(ei, hist);
    scan_kernel<<<1, 256, 0, stream>>>(hist, ofs);
    scatter_kernel<<<NE / 256, 256, 0, stream>>>(ei, ofs, permE, permSrc, permDst);
    edge_mfma<<<EBLK5, 512, 0, stream>>>(ea, permE, permSrc, permDst,
                                         WT, Pp, Qp, b2, b3, sums);
    node_fused<<<NN / 8, 256, 0, stream>>>(x, sums, hist, F1, bf1, F2, bf2,
                                           g0, be0, g1, be1, out);
}